// Round 11
// baseline (274.856 us; speedup 1.0000x reference)
//
#include <hip/hip_runtime.h>
#include <hip/hip_bf16.h>

#define S_LEN  2048
#define DMODEL 2048
#define NH     32
#define NG     8
#define DK     64
#define DV     64

typedef short bf16x8 __attribute__((ext_vector_type(8)));
typedef float f32x4  __attribute__((ext_vector_type(4)));

__device__ __forceinline__ ushort f32_to_bf16(float f) {
    uint u = __float_as_uint(f);
    return (ushort)((u + 0x7fffu + ((u >> 16) & 1u)) >> 16);   // RNE
}
__device__ __forceinline__ float bf16_to_f32(ushort h) {
    return __uint_as_float(((uint)h) << 16);
}
__device__ __forceinline__ uint pack_bf16x2(float a, float b) {
    return (uint)f32_to_bf16(a) | ((uint)f32_to_bf16(b) << 16);
}

// ------------------------------------------- fused cast f32->bf16 (q,k,v in one)
__global__ void cast3_f32_to_bf16(const float* __restrict__ q,
                                  const float* __restrict__ k,
                                  const float* __restrict__ v,
                                  ushort* __restrict__ xq,
                                  ushort* __restrict__ xk,
                                  ushort* __restrict__ xv, int n8) {
    const float* in  = blockIdx.z == 0 ? q  : (blockIdx.z == 1 ? k  : v);
    ushort*      out = blockIdx.z == 0 ? xq : (blockIdx.z == 1 ? xk : xv);
    int i = blockIdx.x * blockDim.x + threadIdx.x;
    const int stride = gridDim.x * blockDim.x;
    for (; i < n8; i += stride) {
        const float4 a = ((const float4*)in)[2 * i];
        const float4 b = ((const float4*)in)[2 * i + 1];
        uint4 o;
        o.x = (uint)f32_to_bf16(a.x) | ((uint)f32_to_bf16(a.y) << 16);
        o.y = (uint)f32_to_bf16(a.z) | ((uint)f32_to_bf16(a.w) << 16);
        o.z = (uint)f32_to_bf16(b.x) | ((uint)f32_to_bf16(b.y) << 16);
        o.w = (uint)f32_to_bf16(b.z) | ((uint)f32_to_bf16(b.w) << 16);
        ((uint4*)out)[i] = o;
    }
}

// ---------------------- fused W[K][N] f32 -> Wt[N][K] bf16 for all four weights
// grid.x block ranges: [0,64) Wq, [64,80) Wk, [80,96) Wv, [96,160) Wo. K=2048.
__global__ void transpose_cast4(const float* __restrict__ Wq,
                                const float* __restrict__ Wk,
                                const float* __restrict__ Wv,
                                const float* __restrict__ Wo,
                                ushort* __restrict__ Wqt, ushort* __restrict__ Wkt,
                                ushort* __restrict__ Wvt, ushort* __restrict__ Wot) {
    __shared__ float t[32][33];
    int bx = blockIdx.x;
    const float* W; ushort* Wt; int N;
    if (bx < 64)      { W = Wq; Wt = Wqt; N = 2048; }
    else if (bx < 80) { W = Wk; Wt = Wkt; N = 512;  bx -= 64; }
    else if (bx < 96) { W = Wv; Wt = Wvt; N = 512;  bx -= 80; }
    else              { W = Wo; Wt = Wot; N = 2048; bx -= 96; }
    const int n0 = bx * 32, k0 = blockIdx.y * 32;
    const int tx = threadIdx.x, ty = threadIdx.y;   // 32 x 8
#pragma unroll
    for (int i = 0; i < 4; ++i)
        t[ty + 8 * i][tx] = W[(size_t)(k0 + ty + 8 * i) * N + n0 + tx];
    __syncthreads();
#pragma unroll
    for (int i = 0; i < 4; ++i)
        Wt[(size_t)(n0 + ty + 8 * i) * 2048 + k0 + tx] = f32_to_bf16(t[tx][ty + 8 * i]);
}

// ------------------------------------------------------------- bf16 MFMA GEMM
// C[M][N] = (A[M][K] @ Bt[N][K]^T + bias) * scale.  128(M)x64(N) tile, 4 waves
// stacked in M (each: 32 rows x 64 cols = 2x4 frags of mfma_f32_16x16x32_bf16).
// BK=64, LDS row stride 72 shorts (144B -> 2-way alias only).  Depth-2
// register prefetch (named sets X/Y).  Requires K % 128 == 0.
// MODE: 0 = bf16 C, 1 = f32 C, 2 = bf16 C^T (V^T, output stride S_LEN) via LDS.
template <int MODE>
__device__ __forceinline__ void gemm_body_128x64(
        const ushort* __restrict__ A, const ushort* __restrict__ Bt,
        const float* __restrict__ bias, void* __restrict__ Cv,
        ushort* As, ushort* Bs, ushort* Ts, int N, int K, float scale,
        int bx, int by) {
    const int tid  = threadIdx.x;
    const int lane = tid & 63, wave = tid >> 6;
    const int l15 = lane & 15, quad = lane >> 4;
    const int row0 = by * 128, col0 = bx * 64;

    f32x4 acc[2][4];
#pragma unroll
    for (int i = 0; i < 2; ++i)
#pragma unroll
        for (int j = 0; j < 4; ++j) { f32x4 z = {0.f,0.f,0.f,0.f}; acc[i][j] = z; }

    // staging coords (BK=64): A 128x64 (4 b128/thread), B 64x64 (2 b128/thread)
    const int ar = tid >> 1, ak = (tid & 1) * 32;
    const int br = tid >> 2, bk = (tid & 3) * 16;
    const ushort* aptr = A  + (size_t)(row0 + ar) * K + ak;
    const ushort* bptr = Bt + (size_t)(col0 + br) * K + bk;

    // set X <- tile 0, set Y <- tile 1 (k=64)
    bf16x8 xa0 = *(const bf16x8*)(aptr);
    bf16x8 xa1 = *(const bf16x8*)(aptr + 8);
    bf16x8 xa2 = *(const bf16x8*)(aptr + 16);
    bf16x8 xa3 = *(const bf16x8*)(aptr + 24);
    bf16x8 xb0 = *(const bf16x8*)(bptr);
    bf16x8 xb1 = *(const bf16x8*)(bptr + 8);
    bf16x8 ya0 = *(const bf16x8*)(aptr + 64);
    bf16x8 ya1 = *(const bf16x8*)(aptr + 72);
    bf16x8 ya2 = *(const bf16x8*)(aptr + 80);
    bf16x8 ya3 = *(const bf16x8*)(aptr + 88);
    bf16x8 yb0 = *(const bf16x8*)(bptr + 64);
    bf16x8 yb1 = *(const bf16x8*)(bptr + 72);

    for (int k0 = 0; k0 < K; k0 += 128) {
        // ---------------- sub-step 0: tile k0 (set X)
        __syncthreads();
        *(bf16x8*)&As[ar * 72 + ak]      = xa0;
        *(bf16x8*)&As[ar * 72 + ak + 8]  = xa1;
        *(bf16x8*)&As[ar * 72 + ak + 16] = xa2;
        *(bf16x8*)&As[ar * 72 + ak + 24] = xa3;
        *(bf16x8*)&Bs[br * 72 + bk]      = xb0;
        *(bf16x8*)&Bs[br * 72 + bk + 8]  = xb1;
        __syncthreads();
        if (k0 + 128 < K) {                       // X <- tile k0+128
            xa0 = *(const bf16x8*)(aptr + k0 + 128);
            xa1 = *(const bf16x8*)(aptr + k0 + 136);
            xa2 = *(const bf16x8*)(aptr + k0 + 144);
            xa3 = *(const bf16x8*)(aptr + k0 + 152);
            xb0 = *(const bf16x8*)(bptr + k0 + 128);
            xb1 = *(const bf16x8*)(bptr + k0 + 136);
        }
#pragma unroll
        for (int kk = 0; kk < 2; ++kk) {
            bf16x8 af[2], bf[4];
#pragma unroll
            for (int mi = 0; mi < 2; ++mi)
                af[mi] = *(const bf16x8*)&As[(wave * 32 + mi * 16 + l15) * 72 + kk * 32 + quad * 8];
#pragma unroll
            for (int ni = 0; ni < 4; ++ni)
                bf[ni] = *(const bf16x8*)&Bs[(ni * 16 + l15) * 72 + kk * 32 + quad * 8];
#pragma unroll
            for (int mi = 0; mi < 2; ++mi)
#pragma unroll
                for (int ni = 0; ni < 4; ++ni)
                    acc[mi][ni] = __builtin_amdgcn_mfma_f32_16x16x32_bf16(
                        af[mi], bf[ni], acc[mi][ni], 0, 0, 0);
        }

        // ---------------- sub-step 1: tile k0+64 (set Y)
        __syncthreads();
        *(bf16x8*)&As[ar * 72 + ak]      = ya0;
        *(bf16x8*)&As[ar * 72 + ak + 8]  = ya1;
        *(bf16x8*)&As[ar * 72 + ak + 16] = ya2;
        *(bf16x8*)&As[ar * 72 + ak + 24] = ya3;
        *(bf16x8*)&Bs[br * 72 + bk]      = yb0;
        *(bf16x8*)&Bs[br * 72 + bk + 8]  = yb1;
        __syncthreads();
        if (k0 + 192 < K) {                       // Y <- tile k0+192
            ya0 = *(const bf16x8*)(aptr + k0 + 192);
            ya1 = *(const bf16x8*)(aptr + k0 + 200);
            ya2 = *(const bf16x8*)(aptr + k0 + 208);
            ya3 = *(const bf16x8*)(aptr + k0 + 216);
            yb0 = *(const bf16x8*)(bptr + k0 + 192);
            yb1 = *(const bf16x8*)(bptr + k0 + 200);
        }
#pragma unroll
        for (int kk = 0; kk < 2; ++kk) {
            bf16x8 af[2], bf[4];
#pragma unroll
            for (int mi = 0; mi < 2; ++mi)
                af[mi] = *(const bf16x8*)&As[(wave * 32 + mi * 16 + l15) * 72 + kk * 32 + quad * 8];
#pragma unroll
            for (int ni = 0; ni < 4; ++ni)
                bf[ni] = *(const bf16x8*)&Bs[(ni * 16 + l15) * 72 + kk * 32 + quad * 8];
#pragma unroll
            for (int mi = 0; mi < 2; ++mi)
#pragma unroll
                for (int ni = 0; ni < 4; ++ni)
                    acc[mi][ni] = __builtin_amdgcn_mfma_f32_16x16x32_bf16(
                        af[mi], bf[ni], acc[mi][ni], 0, 0, 0);
        }
    }

    if (MODE == 2) {
        // ---- V^T epilogue: stage 128(s) x 64(v) accs into LDS as [v][s],
        // then coalesced store to Cv[v][s] with row stride S_LEN.
        __syncthreads();                  // last K-step's LDS reads done
#pragma unroll
        for (int mi = 0; mi < 2; ++mi)
#pragma unroll
            for (int ni = 0; ni < 4; ++ni) {
                const float bv = bias[col0 + ni * 16 + l15];
                const int lrow = wave * 32 + mi * 16 + quad * 4;   // mult of 4
                uint2 uu;
                uu.x = pack_bf16x2((acc[mi][ni][0] + bv) * scale,
                                   (acc[mi][ni][1] + bv) * scale);
                uu.y = pack_bf16x2((acc[mi][ni][2] + bv) * scale,
                                   (acc[mi][ni][3] + bv) * scale);
                *(uint2*)&Ts[(ni * 16 + l15) * 136 + lrow] = uu;
            }
        __syncthreads();
        const int v = tid >> 2, s0 = (tid & 3) * 32;
#pragma unroll
        for (int i = 0; i < 4; ++i) {
            const uint4 d = *(const uint4*)&Ts[v * 136 + s0 + 8 * i];
            *(uint4*)&((ushort*)Cv)[(size_t)(col0 + v) * S_LEN + row0 + s0 + 8 * i] = d;
        }
        return;
    }

#pragma unroll
    for (int mi = 0; mi < 2; ++mi)
#pragma unroll
        for (int ni = 0; ni < 4; ++ni) {
            const int col = col0 + ni * 16 + l15;
            const float bv = bias[col];
#pragma unroll
            for (int reg = 0; reg < 4; ++reg) {
                const int row = row0 + wave * 32 + mi * 16 + quad * 4 + reg;
                const float val = (acc[mi][ni][reg] + bv) * scale;
                if (MODE == 1)
                    ((float*)Cv)[(size_t)row * N + col] = val;
                else
                    ((ushort*)Cv)[(size_t)row * N + col] = f32_to_bf16(val);
            }
        }
}

// XCD-aware 2D-chunk decode for 512-block GEMMs (32 col-tiles x 16 row-tiles).
__device__ __forceinline__ void xcd_decode_32x16(int d, int& bx, int& by) {
    const int xcd = d & 7, i = d >> 3;          // i in [0,64)
    bx = (xcd & 3) * 8 + (i & 7);
    by = (xcd >> 2) * 8 + (i >> 3);
}

// Q projection: [2048,2048]x[2048,2048], bf16 out, scale folded
__global__ __launch_bounds__(256) void gemm_q(
        const ushort* __restrict__ A, const ushort* __restrict__ Bt,
        const float* __restrict__ bias, ushort* __restrict__ Cv, int K,
        float scale) {
    __shared__ ushort smem[128 * 72 + 64 * 72];
    int bx, by; xcd_decode_32x16(blockIdx.x, bx, by);
    gemm_body_128x64<0>(A, Bt, bias, Cv, smem, smem + 128 * 72, nullptr,
                        2048, K, scale, bx, by);
}

// O projection: f32 out
__global__ __launch_bounds__(256) void gemm_o(
        const ushort* __restrict__ A, const ushort* __restrict__ Bt,
        const float* __restrict__ bias, float* __restrict__ Cv, int K) {
    __shared__ ushort smem[128 * 72 + 64 * 72];
    int bx, by; xcd_decode_32x16(blockIdx.x, bx, by);
    gemm_body_128x64<1>(A, Bt, bias, Cv, smem, smem + 128 * 72, nullptr,
                        2048, K, 1.0f, bx, by);
}

// K and V projections fused via gridDim.z; V writes V^T directly (MODE 2).
__global__ __launch_bounds__(256) void gemm_kv(
        const ushort* __restrict__ Xk, const ushort* __restrict__ Xv,
        const ushort* __restrict__ Wkt, const ushort* __restrict__ Wvt,
        const float* __restrict__ bk, const float* __restrict__ bv,
        ushort* __restrict__ Kb, ushort* __restrict__ Vtp, int K) {
    __shared__ ushort smem[128 * 72 + 64 * 72];   // 13824 shorts; Ts needs 8704
    ushort* As = smem;
    ushort* Bs = smem + 128 * 72;
    if (blockIdx.z == 0)
        gemm_body_128x64<0>(Xk, Wkt, bk, Kb, As, Bs, nullptr, 512, K, 1.0f,
                            blockIdx.x, blockIdx.y);
    else
        gemm_body_128x64<2>(Xv, Wvt, bv, Vtp, As, Bs, smem, 512, K, 1.0f,
                            blockIdx.x, blockIdx.y);
}

// ------------------------------------------------------ MFMA flash attention
// Grid (32 h, 16 y), 256 threads = 4 waves.  Block owns the paired q-tiles
// {y, 31-y}.  KVBLK=128: per-sel iterations = ceil((qt+1)/2) -> pair total =
// 17 for EVERY y (uniform block length, free).  Halves barriers, shfl_xor
// reductions, and rescale passes per key vs KVBLK=64 (the per-iteration
// fixed overhead that round-10 showed to be the binding cost).  Last tile
// masks via key > row + roff (roff=64 when qt odd: tile base = (qt-1)*64).
// Memory always in-bounds (max 16 tiles = 2048 keys).
// LDS: K[128][72] + V^T[64][136] + P[4][16][136] = 53.2 KB -> 2 blocks/CU.
//
// SWAPPED-OPERAND core (unchanged): S^T = mfma(K,Q) puts q in the C-layout
// column; m,l scalar per lane; P^T via per-wave LDS; O^T = mfma(V^T,P^T).
// Scale (1/sqrt(dk)*log2e) pre-folded into Q; exp = exp2; defer-max (T13).
__global__ __launch_bounds__(256) void gqa_attn_mfma(
        const ushort* __restrict__ Qb, const ushort* __restrict__ Kb,
        const ushort* __restrict__ Vt, ushort* __restrict__ Ab) {
    __shared__ ushort Ks[128 * 72];      // [key][d]
    __shared__ ushort Vs[64 * 136];      // [d][key]
    __shared__ ushort Ps[4][16 * 136];   // per-wave P^T as [q][key]

    const int h    = blockIdx.x, g = h >> 2;
    const int y    = blockIdx.y;
    const int tid  = threadIdx.x;
    const int lane = tid & 63, wave = tid >> 6;
    const int l15  = lane & 15, quad = lane >> 4;
    const float DEFER_THR = 11.5416f;    // 8 * log2(e)

    // staging coords: K 128 rows x 64 d (32 shorts/thread);
    //                 V^T 64 rows x 128 keys (32 shorts/thread)
    const int krow = tid >> 1, kch = (tid & 1) * 32;
    const int vrow = tid >> 2, vch = (tid & 3) * 32;
    const ushort* kbase = Kb + (size_t)krow * (NG * DK) + g * DK + kch;
    const ushort* vbase = Vt + (size_t)(g * 64 + vrow) * S_LEN + vch;
    const size_t krstep = (size_t)(NG * DK);     // bytes-in-shorts per key row

    for (int sel = 0; sel < 2; ++sel) {
        const int qt = sel ? (31 - y) : y;
        const int qr = qt * 64 + wave * 16;      // wave's first q row
        const int roff = (qt & 1) ? 64 : 0;      // diag offset in last 128-tile
        const int iters = (qt >> 1) + 1;         // ceil((qt+1)/2)

        // Q frags (scale pre-folded), d=0..31 / 32..63
        bf16x8 qa0, qa1;
        {
            const size_t base = (size_t)(qr + l15) * (NH * DK) + (size_t)h * DK + quad * 8;
            qa0 = *(const bf16x8*)&Qb[base];
            qa1 = *(const bf16x8*)&Qb[base + 32];
        }

        f32x4 o[4];                      // O^T: lane = q (l15); rows = d
#pragma unroll
        for (int dt = 0; dt < 4; ++dt) { f32x4 z = {0.f,0.f,0.f,0.f}; o[dt] = z; }
        float m = -1e30f;                // per-lane running max (log2 domain)
        float l = 0.f;                   // per-lane running sum

        // preload tile 0 (keys 0..127)
        bf16x8 kr[4], vr[4];
#pragma unroll
        for (int i = 0; i < 4; ++i) {
            kr[i] = *(const bf16x8*)(kbase + 8 * i);
            vr[i] = *(const bf16x8*)(vbase + 8 * i);
        }

        for (int it = 0; it < iters; ++it) {
            __syncthreads();             // prior LDS reads complete
#pragma unroll
            for (int i = 0; i < 4; ++i) {
                *(bf16x8*)&Ks[krow * 72 + kch + 8 * i]  = kr[i];
                *(bf16x8*)&Vs[vrow * 136 + vch + 8 * i] = vr[i];
            }
            __syncthreads();

            // prefetch tile it+1 (keys (it+1)*128 ..)
            if (it + 1 < iters) {
                const size_t ko = (size_t)(it + 1) * 128 * krstep;
                const size_t vo = (size_t)(it + 1) * 128;
#pragma unroll
                for (int i = 0; i < 4; ++i) {
                    kr[i] = *(const bf16x8*)(kbase + ko + 8 * i);
                    vr[i] = *(const bf16x8*)(vbase + vo + 8 * i);
                }
            }

            // S^T = K Q^T over 128 keys: kt 0..7
            f32x4 s[8];
#pragma unroll
            for (int kt = 0; kt < 8; ++kt) {
                const bf16x8 kb0 = *(const bf16x8*)&Ks[(kt * 16 + l15) * 72 + quad * 8];
                const bf16x8 kb1 = *(const bf16x8*)&Ks[(kt * 16 + l15) * 72 + 32 + quad * 8];
                f32x4 acc = {0.f, 0.f, 0.f, 0.f};
                acc = __builtin_amdgcn_mfma_f32_16x16x32_bf16(kb0, qa0, acc, 0, 0, 0);
                acc = __builtin_amdgcn_mfma_f32_16x16x32_bf16(kb1, qa1, acc, 0, 0, 0);
                s[kt] = acc;
            }

            // causal mask (last tile only; covers diag + overflow half)
            if (it == iters - 1) {
                const int row = wave * 16 + l15 + roff;
#pragma unroll
                for (int kt = 0; kt < 8; ++kt)
#pragma unroll
                    for (int r = 0; r < 4; ++r) {
                        const int key = kt * 16 + quad * 4 + r;
                        if (key > row) s[kt][r] = -1e30f;
                    }
            }

            // tile max: 31 in-lane + cross-quad (xor 16, 32)
            float pmax;
            {
                float t[8];
#pragma unroll
                for (int kt = 0; kt < 8; ++kt)
                    t[kt] = fmaxf(fmaxf(s[kt][0], s[kt][1]), fmaxf(s[kt][2], s[kt][3]));
                const float u0 = fmaxf(fmaxf(t[0], t[1]), fmaxf(t[2], t[3]));
                const float u1 = fmaxf(fmaxf(t[4], t[5]), fmaxf(t[6], t[7]));
                pmax = fmaxf(u0, u1);
            }
            pmax = fmaxf(pmax, __shfl_xor(pmax, 16, 64));
            pmax = fmaxf(pmax, __shfl_xor(pmax, 32, 64));

            // defer-max rescale
            if (!__all(pmax - m <= DEFER_THR)) {
                const float mnew  = fmaxf(m, pmax);
                const float alpha = __builtin_amdgcn_exp2f(m - mnew);
                l *= alpha;
#pragma unroll
                for (int dt = 0; dt < 4; ++dt)
#pragma unroll
                    for (int r = 0; r < 4; ++r) o[dt][r] *= alpha;
                m = mnew;
            }

            // exp2 + pack + per-wave LDS store; accumulate row sum
            ushort* Pw = &Ps[wave][0];
            float rsum = 0.f;
#pragma unroll
            for (int kt = 0; kt < 8; ++kt) {
                const float p0 = __builtin_amdgcn_exp2f(s[kt][0] - m);
                const float p1 = __builtin_amdgcn_exp2f(s[kt][1] - m);
                const float p2 = __builtin_amdgcn_exp2f(s[kt][2] - m);
                const float p3 = __builtin_amdgcn_exp2f(s[kt][3] - m);
                rsum += (p0 + p1) + (p2 + p3);
                uint2 uu;
                uu.x = pack_bf16x2(p0, p1);
                uu.y = pack_bf16x2(p2, p3);
                *(uint2*)&Pw[l15 * 136 + kt * 16 + quad * 4] = uu;
            }
            rsum += __shfl_xor(rsum, 16, 64);
            rsum += __shfl_xor(rsum, 32, 64);
            l += rsum;

            // O^T += V^T P^T over 128 keys (kc = 32-key chunks)
#pragma unroll
            for (int kc = 0; kc < 4; ++kc) {
                const bf16x8 pa = *(const bf16x8*)&Pw[l15 * 136 + kc * 32 + quad * 8];
#pragma unroll
                for (int dt = 0; dt < 4; ++dt) {
                    const bf16x8 vb = *(const bf16x8*)&Vs[(dt * 16 + l15) * 136 + kc * 32 + quad * 8];
                    o[dt] = __builtin_amdgcn_mfma_f32_16x16x32_bf16(vb, pa, o[dt], 0, 0, 0);
                }
            }
        }

        // epilogue: lane holds O^T[d = dt*16 + quad*4 + r][q = l15]
        const float invl = 1.0f / l;
#pragma unroll
        for (int dt = 0; dt < 4; ++dt) {
            uint2 uu;
            uu.x = pack_bf16x2(o[dt][0] * invl, o[dt][1] * invl);
            uu.y = pack_bf16x2(o[dt][2] * invl, o[dt][3] * invl);
            *(uint2*)&Ab[(size_t)(qr + l15) * (NH * DV) + (size_t)h * DV + dt * 16 + quad * 4] = uu;
        }
    }
}

// ---------------------------------------------------------------------------
extern "C" void kernel_launch(void* const* d_in, const int* in_sizes, int n_in,
                              void* d_out, int out_size, void* d_ws, size_t ws_size,
                              hipStream_t stream) {
    const float* queries = (const float*)d_in[0];
    const float* keys    = (const float*)d_in[1];
    const float* values  = (const float*)d_in[2];
    const float* Wq      = (const float*)d_in[3];
    const float* bq      = (const float*)d_in[4];
    const float* Wk      = (const float*)d_in[5];
    const float* bk      = (const float*)d_in[6];
    const float* Wv      = (const float*)d_in[7];
    const float* bv      = (const float*)d_in[8];
    const float* Wo      = (const float*)d_in[9];
    const float* bo      = (const float*)d_in[10];
    float* out = (float*)d_out;

    const size_t MB = 1024 * 1024;
    unsigned char* w = (unsigned char*)d_ws;
    ushort* Xq  = (ushort*)(w + 0 * MB);    // [2048][2048] bf16
    ushort* Xk  = (ushort*)(w + 8 * MB);
    ushort* Xv  = (ushort*)(w + 16 * MB);
    ushort* Wqt = (ushort*)(w + 24 * MB);   // [2048][2048]
    ushort* Wkt = (ushort*)(w + 32 * MB);   // [512][2048]
    ushort* Wvt = (ushort*)(w + 34 * MB);
    ushort* Wot = (ushort*)(w + 36 * MB);   // [2048][2048]
    ushort* Qb  = (ushort*)(w + 44 * MB);   // [2048][2048]
    ushort* Kb  = (ushort*)(w + 52 * MB);   // [2048][512]
    ushort* Vtp = (ushort*)(w + 54 * MB);   // V^T [512][2048] (written directly)
    ushort* Ab  = (ushort*)(w + 56 * MB);   // [2048][2048]

    const int n8 = (S_LEN * DMODEL) / 8;
    cast3_f32_to_bf16<<<dim3(1024, 1, 3), 256, 0, stream>>>(
        queries, keys, values, Xq, Xk, Xv, n8);

    dim3 tb(32, 8);
    transpose_cast4<<<dim3(160, 64), tb, 0, stream>>>(
        Wq, Wk, Wv, Wo, Wqt, Wkt, Wvt, Wot);

    // Q projection (XCD-swizzled); softmax scale * log2(e) folded into Q
    const float QSCALE = 0.125f * 1.44269504f;
    gemm_q<<<512, 256, 0, stream>>>(Xq, Wqt, bq, Qb, DMODEL, QSCALE);

    // K and V projections fused (z=0: K, z=1: V -> V^T direct)
    gemm_kv<<<dim3(8, 16, 2), 256, 0, stream>>>(
        Xk, Xv, Wkt, Wvt, bk, bv, Kb, Vtp, DMODEL);

    // attention: 512 uniform-length blocks (KVBLK=128, paired q-tiles)
    gqa_attn_mfma<<<dim3(32, 16), 256, 0, stream>>>(Qb, Kb, Vtp, Ab);

    // O projection (XCD-swizzled): [2048,2048] @ [2048,2048] -> f32 out
    gemm_o<<<512, 256, 0, stream>>>(Ab, Wot, bo, out, DMODEL);
}